// Round 7
// baseline (138.868 us; speedup 1.0000x reference)
//
#include <hip/hip_runtime.h>
#include <hip/hip_bf16.h>
#include <math.h>

// Problem constants
#define DD 1024   // D
#define HH 4096   // H
#define EE 8      // experts
#define MTOK 4096 // B*S tokens
#define MROWS 8192 // MTOK*K rows of the packed GEMM A operand

typedef __attribute__((ext_vector_type(8))) short bf16x8;
typedef __attribute__((ext_vector_type(4))) float f32x4;
typedef __attribute__((ext_vector_type(16))) float f32x16;

__device__ __forceinline__ unsigned short f2bf(float x){
  __hip_bfloat16 h = __float2bfloat16(x);
  return *reinterpret_cast<unsigned short*>(&h);
}

__device__ __forceinline__ void gload16(const void* g, void* l){
  __builtin_amdgcn_global_load_lds((__attribute__((address_space(1))) void*)g,
                                   (__attribute__((address_space(3))) void*)l,
                                   16, 0, 0);
}

// ---------------- fused W->bf16 + column stats ----------------
__global__ void cvtstats_kernel(const float4* __restrict__ W4, ushort4* __restrict__ Wb4,
                                float* __restrict__ pmean, float* __restrict__ pm2){
  int rc = blockIdx.x;          // 0..127
  int tid = threadIdx.x;        // 0..255 -> columns 4*tid..4*tid+3
  double s0=0,s1=0,s2_=0,s3=0, q0=0,q1=0,q2=0,q3=0;
  for (int h = rc * 32; h < rc * 32 + 32; ++h){
    float4 w = W4[(size_t)h * 256 + tid];
    Wb4[(size_t)h * 256 + tid] = make_ushort4(f2bf(w.x), f2bf(w.y), f2bf(w.z), f2bf(w.w));
    s0 += w.x; q0 += (double)w.x * w.x;
    s1 += w.y; q1 += (double)w.y * w.y;
    s2_ += w.z; q2 += (double)w.z * w.z;
    s3 += w.w; q3 += (double)w.w * w.w;
  }
  int d0 = rc * DD + tid * 4;
  pmean[d0]   = (float)s0;  pm2[d0]   = (float)q0;
  pmean[d0+1] = (float)s1;  pm2[d0+1] = (float)q1;
  pmean[d0+2] = (float)s2_; pm2[d0+2] = (float)q2;
  pmean[d0+3] = (float)s3;  pm2[d0+3] = (float)q3;
}

__global__ void colstats_final_kernel(const float* __restrict__ pmean,
                                      const float* __restrict__ pm2,
                                      double* __restrict__ cmean, double* __restrict__ cvar){
  int d = blockIdx.x * 256 + threadIdx.x; // 4 blocks x 256
  double s = 0.0, s2 = 0.0;
  for (int c = 0; c < 128; ++c){ s += (double)pmean[c * DD + d]; s2 += (double)pm2[c * DD + d]; }
  double m = s / (double)HH;
  cmean[d] = m;
  cvar[d]  = s2 / (double)HH - m * m;  // unbiased=False variance of column d
}

__global__ void biasmean_kernel(const float* __restrict__ bias, double* __restrict__ bmean){
  __shared__ double red[256];
  double s = 0.0;
  for (int h = threadIdx.x; h < HH; h += 256) s += (double)bias[h];
  red[threadIdx.x] = s;
  __syncthreads();
  for (int k = 128; k > 0; k >>= 1){
    if (threadIdx.x < k) red[threadIdx.x] += red[threadIdx.x + k];
    __syncthreads();
  }
  if (threadIdx.x == 0) *bmean = red[0] / (double)HH;
}

// ---------------- precompute router projection vectors ----------------
__global__ void muvw_kernel(const float* __restrict__ alpha, const float* __restrict__ beta,
                            const double* __restrict__ cmean, const double* __restrict__ cvar,
                            float* __restrict__ muw, float* __restrict__ vw){
  int i = blockIdx.x * 256 + threadIdx.x;  // 32 blocks -> 8192
  int d = i & (DD - 1);
  double a = (double)alpha[i];
  muw[i] = (float)(a * cmean[d] + (double)beta[i]);
  vw[i]  = (float)(a * a * cvar[d]);
}

// ---------------- router: one wave per token, fused Xs build ----------------
__global__ __launch_bounds__(256) void router_kernel(const float4* __restrict__ x4,
                                                     const float4* __restrict__ alpha4,
                                                     const float4* __restrict__ muw4,
                                                     const float4* __restrict__ vw4,
                                                     const double* __restrict__ bmeanp,
                                                     unsigned short* __restrict__ Xs,
                                                     float2* __restrict__ wpair){
  int wv = threadIdx.x >> 6, lane = threadIdx.x & 63;
  int t = blockIdx.x * 4 + wv;                       // token
  const float4* xt = x4 + (size_t)t * 256;

  float4 xv[4];
  double mu[EE], s2[EE];
  #pragma unroll
  for (int e = 0; e < EE; ++e){ mu[e] = 0.0; s2[e] = 0.0; }

  #pragma unroll
  for (int r = 0; r < 4; ++r){
    int c = lane + 64 * r;                           // float4 index 0..255
    float4 xf = xt[c];
    xv[r] = xf;
    float x2x = xf.x * xf.x, x2y = xf.y * xf.y, x2z = xf.z * xf.z, x2w = xf.w * xf.w;
    #pragma unroll
    for (int e = 0; e < EE; ++e){
      float4 m4 = muw4[e * 256 + c];
      float4 v4 = vw4[e * 256 + c];
      mu[e] += (double)xf.x * m4.x + (double)xf.y * m4.y
             + (double)xf.z * m4.z + (double)xf.w * m4.w;
      s2[e] += (double)x2x * v4.x + (double)x2y * v4.y
             + (double)x2z * v4.z + (double)x2w * v4.w;
    }
  }

  #pragma unroll
  for (int off = 32; off > 0; off >>= 1){
    #pragma unroll
    for (int e = 0; e < EE; ++e){
      mu[e] += __shfl_xor(mu[e], off);
      s2[e] += __shfl_xor(s2[e], off);
    }
  }

  // rank by z = m / sqrt(2v)  (erf is monotonic)
  double bm = *bmeanp;
  double z[EE];
  #pragma unroll
  for (int e = 0; e < EE; ++e){
    double m = mu[e] + bm;
    double v = s2[e] + 1e-8;
    z[e] = m / sqrt(2.0 * v);
  }
  int e1 = 0;
  #pragma unroll
  for (int e = 1; e < EE; ++e) if (z[e] > z[e1]) e1 = e;
  int e2 = -1;
  #pragma unroll
  for (int e = 0; e < EE; ++e){
    if (e == e1) continue;
    if (e2 < 0 || z[e] > z[e2]) e2 = e;
  }
  double lg1 = erf(z[e1]), lg2 = erf(z[e2]);
  double ex = exp(lg2 - lg1);                        // lg2 <= lg1
  float w1 = (float)(1.0 / (1.0 + ex));
  float w2 = (float)(ex / (1.0 + ex));
  if (lane == 0) wpair[t] = make_float2(w1, w2);

  const float4* a1 = alpha4 + (size_t)e1 * 256;
  const float4* a2 = alpha4 + (size_t)e2 * 256;
  ushort4* X1 = (ushort4*)(Xs + (size_t)(2 * t) * DD);
  ushort4* X2 = (ushort4*)(Xs + (size_t)(2 * t + 1) * DD);
  #pragma unroll
  for (int r = 0; r < 4; ++r){
    int c = lane + 64 * r;
    float4 xf = xv[r];
    float4 av = a1[c];
    X1[c] = make_ushort4(f2bf(xf.x * av.x), f2bf(xf.y * av.y),
                         f2bf(xf.z * av.z), f2bf(xf.w * av.w));
    av = a2[c];
    X2[c] = make_ushort4(f2bf(xf.x * av.x), f2bf(xf.y * av.y),
                         f2bf(xf.z * av.z), f2bf(xf.w * av.w));
  }
}

// ---------------- GEMM: C[8192,4096] = Xs @ Wb^T, fused relu+bias+combine ----------------
// r4-verified structure (128x128 tile, BK=64, dbuf, counted vmcnt(8), XOR
// chunk swizzle via pre-swizzled source, 2 blocks/CU) with 32x32x16 MFMA:
// -33% LDS fragment traffic (1KB frag feeds 32 rows), half the issue slots,
// faster measured pipe (m119: 2495 TF).
#define BM 128
#define BN 128
#define BKT 64
#define NKT (DD / BKT)     // 16
#define SLOTE (BM * BKT)   // 8192 elems = 16KB per slot

__global__ __launch_bounds__(256, 2) void gemm_kernel(const unsigned short* __restrict__ Xs,
                                                      const unsigned short* __restrict__ Wb,
                                                      const float* __restrict__ bias,
                                                      const float2* __restrict__ wpair,
                                                      float* __restrict__ out){
  __shared__ __align__(16) unsigned short As[2 * SLOTE]; // 32 KB
  __shared__ __align__(16) unsigned short Bs[2 * SLOTE]; // 32 KB

  int tid = threadIdx.x, lane = tid & 63, wv = tid >> 6;
  int wr = wv >> 1, wc = wv & 1;            // wave tile 64x64
  int l31 = lane & 31, lh = lane >> 5;

  // XCD swizzle: 2048 blocks = 8 chunks x 256; chunk owns 8 M-tiles x 32 N-tiles
  int bid = blockIdx.x;
  int ch = bid & 7, local = bid >> 3;
  int mtile = ch * 8 + (local & 7);         // 0..63
  int ntile = local >> 3;                   // 0..31
  int bm0 = mtile * BM, bn0 = ntile * BN;

  // --- staging (per wave: rows 32wv..32wv+31, 4 batches of 8 rows; lane ->
  //     row rl within batch, chunk cg pre-swizzled so LDS fill is linear) ---
  int rl = lane >> 3;                       // 0..7
  int cg = (lane & 7) ^ rl;                 // involution
  const unsigned short* gA = Xs + (size_t)(bm0 + 32 * wv + rl) * DD + cg * 8;
  const unsigned short* gB = Wb + (size_t)(bn0 + 32 * wv + rl) * DD + cg * 8;
  unsigned short* lA = As + 32 * wv * BKT + lane * 8;
  unsigned short* lB = Bs + 32 * wv * BKT + lane * 8;

  auto stage = [&](int kt, int slot){
    int koff = kt * BKT;
    #pragma unroll
    for (int j = 0; j < 4; ++j){
      gload16(gA + (size_t)(8 * j) * DD + koff, lA + slot * SLOTE + j * 512);
      gload16(gB + (size_t)(8 * j) * DD + koff, lB + slot * SLOTE + j * 512);
    }
  };

  // --- read addressing: row_local = {wr|wc}*64 + ab*32 + l31 ---
  // k-octet for lane: (lane>>5)*8 + ks*16 -> chunk = 2*ks + lh, swizzled ^ (row&7)
  int r7 = l31 & 7;                          // (row_local & 7), ab*32 doesn't affect
  int arow = (wr * 64 + l31) * BKT;
  int brow = (wc * 64 + l31) * BKT;

  f32x16 acc[2][2] = {};
  bf16x8 af[2][4], bf[2][4];

  stage(0, 0);
  #pragma unroll 1
  for (int t = 0; t < NKT; ++t){
    int slot = t & 1;
    if (t < NKT - 1){
      stage(t + 1, slot ^ 1);
      asm volatile("s_waitcnt vmcnt(8)" ::: "memory");  // tile t resident
    } else {
      asm volatile("s_waitcnt vmcnt(0)" ::: "memory");
    }
    __builtin_amdgcn_s_barrier();

    const unsigned short* Ab = As + slot * SLOTE;
    const unsigned short* Bb = Bs + slot * SLOTE;
    #pragma unroll
    for (int ks = 0; ks < 4; ++ks){
      int chk = ((2 * ks + lh) ^ r7) * 8;
      #pragma unroll
      for (int ab = 0; ab < 2; ++ab){
        af[ab][ks] = *(const bf16x8*)(Ab + arow + ab * (32 * BKT) + chk);
        bf[ab][ks] = *(const bf16x8*)(Bb + brow + ab * (32 * BKT) + chk);
      }
    }

    __builtin_amdgcn_s_setprio(1);
    #pragma unroll
    for (int ks = 0; ks < 4; ++ks)
      #pragma unroll
      for (int ab = 0; ab < 2; ++ab)
        #pragma unroll
        for (int bb = 0; bb < 2; ++bb)
          acc[ab][bb] = __builtin_amdgcn_mfma_f32_32x32x16_bf16(af[ab][ks], bf[bb][ks],
                                                               acc[ab][bb], 0, 0, 0);
    __builtin_amdgcn_s_setprio(0);

    asm volatile("s_waitcnt lgkmcnt(0)" ::: "memory");
    __builtin_amdgcn_s_barrier();
  }

  // epilogue: C/D 32x32 layout col=lane&31, row=(reg&3)+8*(reg>>2)+4*(lane>>5)
  // row pairs (2t,2t+1) are reg pairs (4q+2p, 4q+2p+1) -> lane-local combine
  #pragma unroll
  for (int ab = 0; ab < 2; ++ab)
    #pragma unroll
    for (int bb = 0; bb < 2; ++bb){
      int gh = bn0 + wc * 64 + bb * 32 + l31;
      float bz = bias[gh];
      #pragma unroll
      for (int q = 0; q < 4; ++q)
        #pragma unroll
        for (int p = 0; p < 2; ++p){
          int row = 8 * q + 4 * lh + 2 * p;
          int gm = bm0 + wr * 64 + ab * 32 + row;   // even
          int tt = gm >> 1;
          float2 w = wpair[tt];
          float v0 = acc[ab][bb][4 * q + 2 * p]     + bz;
          float v1 = acc[ab][bb][4 * q + 2 * p + 1] + bz;
          out[(size_t)tt * HH + gh] = w.x * fmaxf(v0, 0.f) + w.y * fmaxf(v1, 0.f);
        }
    }
}

extern "C" void kernel_launch(void* const* d_in, const int* in_sizes, int n_in,
                              void* d_out, int out_size, void* d_ws, size_t ws_size,
                              hipStream_t stream) {
  const float* x     = (const float*)d_in[0];
  const float* W     = (const float*)d_in[1];
  const float* bias  = (const float*)d_in[2];
  const float* alpha = (const float*)d_in[3];
  const float* beta  = (const float*)d_in[4];
  float* out = (float*)d_out;

  char* ws = (char*)d_ws;
  unsigned short* Wb = (unsigned short*)ws;                       // 8 MB
  unsigned short* Xs = (unsigned short*)(ws + (8u << 20));        // 16 MB
  float2* wpair      = (float2*)(ws + (24u << 20));               // 32 KB
  double* cmean      = (double*)(ws + (24u << 20) + (64u << 10)); // 8 KB
  double* cvar       = cmean + DD;                                // 8 KB
  double* bmean      = cvar + DD;                                 // 8 B
  float* pmean       = (float*)(ws + (24u << 20) + (128u << 10)); // 512 KB
  float* pm2         = pmean + 128 * DD;                          // 512 KB
  float* muw         = (float*)(ws + (26u << 20));                // 32 KB
  float* vw          = muw + EE * DD;                             // 32 KB

  cvtstats_kernel<<<128, 256, 0, stream>>>((const float4*)W, (ushort4*)Wb, pmean, pm2);
  colstats_final_kernel<<<4, 256, 0, stream>>>(pmean, pm2, cmean, cvar);
  biasmean_kernel<<<1, 256, 0, stream>>>(bias, bmean);
  muvw_kernel<<<32, 256, 0, stream>>>(alpha, beta, cmean, cvar, muw, vw);
  router_kernel<<<MTOK / 4, 256, 0, stream>>>((const float4*)x, (const float4*)alpha,
                                              (const float4*)muw, (const float4*)vw,
                                              bmean, Xs, wpair);
  gemm_kernel<<<(MROWS / BM) * (HH / BN), 256, 0, stream>>>(Xs, Wb, bias, wpair, out);
}

// Round 8
// 115.531 us; speedup vs baseline: 1.2020x; 1.2020x over previous
//
#include <hip/hip_runtime.h>
#include <hip/hip_bf16.h>
#include <math.h>

// Problem constants
#define DD 1024   // D
#define HH 4096   // H
#define EE 8      // experts
#define MTOK 4096 // B*S tokens
#define MROWS 8192 // MTOK*K rows of the packed GEMM A operand

typedef __attribute__((ext_vector_type(8))) short bf16x8;
typedef __attribute__((ext_vector_type(4))) float f32x4;

__device__ __forceinline__ unsigned short f2bf(float x){
  __hip_bfloat16 h = __float2bfloat16(x);
  return *reinterpret_cast<unsigned short*>(&h);
}

__device__ __forceinline__ void gload16(const void* g, void* l){
  __builtin_amdgcn_global_load_lds((__attribute__((address_space(1))) void*)g,
                                   (__attribute__((address_space(3))) void*)l,
                                   16, 0, 0);
}

// ---------------- fused W->bf16 + column stats ----------------
__global__ void cvtstats_kernel(const float4* __restrict__ W4, ushort4* __restrict__ Wb4,
                                float* __restrict__ pmean, float* __restrict__ pm2){
  int rc = blockIdx.x;          // 0..127
  int tid = threadIdx.x;        // 0..255 -> columns 4*tid..4*tid+3
  double s0=0,s1=0,s2_=0,s3=0, q0=0,q1=0,q2=0,q3=0;
  for (int h = rc * 32; h < rc * 32 + 32; ++h){
    float4 w = W4[(size_t)h * 256 + tid];
    Wb4[(size_t)h * 256 + tid] = make_ushort4(f2bf(w.x), f2bf(w.y), f2bf(w.z), f2bf(w.w));
    s0 += w.x; q0 += (double)w.x * w.x;
    s1 += w.y; q1 += (double)w.y * w.y;
    s2_ += w.z; q2 += (double)w.z * w.z;
    s3 += w.w; q3 += (double)w.w * w.w;
  }
  int d0 = rc * DD + tid * 4;
  pmean[d0]   = (float)s0;  pm2[d0]   = (float)q0;
  pmean[d0+1] = (float)s1;  pm2[d0+1] = (float)q1;
  pmean[d0+2] = (float)s2_; pm2[d0+2] = (float)q2;
  pmean[d0+3] = (float)s3;  pm2[d0+3] = (float)q3;
}

// ---------------- fused finalize: col stats -> muw/vw, bias mean ----------------
__global__ void finalize_kernel(const float* __restrict__ pmean, const float* __restrict__ pm2,
                                const float* __restrict__ bias,
                                const float* __restrict__ alpha, const float* __restrict__ beta,
                                double* __restrict__ bmean,
                                float* __restrict__ muw, float* __restrict__ vw){
  int tid = threadIdx.x;
  int d = blockIdx.x * 256 + tid;     // 4 blocks x 256
  double s = 0.0, s2 = 0.0;
  for (int c = 0; c < 128; ++c){ s += (double)pmean[c * DD + d]; s2 += (double)pm2[c * DD + d]; }
  double m = s / (double)HH;
  double v = s2 / (double)HH - m * m;  // unbiased=False variance

  #pragma unroll
  for (int e = 0; e < EE; ++e){
    double a = (double)alpha[e * DD + d];
    muw[e * DD + d] = (float)(a * m + (double)beta[e * DD + d]);
    vw[e * DD + d]  = (float)(a * a * v);
  }

  if (blockIdx.x == 0){
    __shared__ double red[256];
    double bs = 0.0;
    for (int h = tid; h < HH; h += 256) bs += (double)bias[h];
    red[tid] = bs;
    __syncthreads();
    for (int k = 128; k > 0; k >>= 1){
      if (tid < k) red[tid] += red[tid + k];
      __syncthreads();
    }
    if (tid == 0) *bmean = red[0] / (double)HH;
  }
}

// ---------------- router: one wave per token, fused Xs build ----------------
__global__ __launch_bounds__(256) void router_kernel(const float4* __restrict__ x4,
                                                     const float4* __restrict__ alpha4,
                                                     const float4* __restrict__ muw4,
                                                     const float4* __restrict__ vw4,
                                                     const double* __restrict__ bmeanp,
                                                     unsigned short* __restrict__ Xs,
                                                     float2* __restrict__ wpair){
  int wv = threadIdx.x >> 6, lane = threadIdx.x & 63;
  int t = blockIdx.x * 4 + wv;                       // token
  const float4* xt = x4 + (size_t)t * 256;

  float4 xv[4];
  double mu[EE], s2[EE];
  #pragma unroll
  for (int e = 0; e < EE; ++e){ mu[e] = 0.0; s2[e] = 0.0; }

  #pragma unroll
  for (int r = 0; r < 4; ++r){
    int c = lane + 64 * r;                           // float4 index 0..255
    float4 xf = xt[c];
    xv[r] = xf;
    float x2x = xf.x * xf.x, x2y = xf.y * xf.y, x2z = xf.z * xf.z, x2w = xf.w * xf.w;
    #pragma unroll
    for (int e = 0; e < EE; ++e){
      float4 m4 = muw4[e * 256 + c];
      float4 v4 = vw4[e * 256 + c];
      mu[e] += (double)xf.x * m4.x + (double)xf.y * m4.y
             + (double)xf.z * m4.z + (double)xf.w * m4.w;
      s2[e] += (double)x2x * v4.x + (double)x2y * v4.y
             + (double)x2z * v4.z + (double)x2w * v4.w;
    }
  }

  #pragma unroll
  for (int off = 32; off > 0; off >>= 1){
    #pragma unroll
    for (int e = 0; e < EE; ++e){
      mu[e] += __shfl_xor(mu[e], off);
      s2[e] += __shfl_xor(s2[e], off);
    }
  }

  // rank by z = m / sqrt(2v)  (erf is monotonic)
  double bm = *bmeanp;
  double z[EE];
  #pragma unroll
  for (int e = 0; e < EE; ++e){
    double m = mu[e] + bm;
    double v = s2[e] + 1e-8;
    z[e] = m / sqrt(2.0 * v);
  }
  int e1 = 0;
  #pragma unroll
  for (int e = 1; e < EE; ++e) if (z[e] > z[e1]) e1 = e;
  int e2 = -1;
  #pragma unroll
  for (int e = 0; e < EE; ++e){
    if (e == e1) continue;
    if (e2 < 0 || z[e] > z[e2]) e2 = e;
  }
  double lg1 = erf(z[e1]), lg2 = erf(z[e2]);
  double ex = exp(lg2 - lg1);                        // lg2 <= lg1
  float w1 = (float)(1.0 / (1.0 + ex));
  float w2 = (float)(ex / (1.0 + ex));
  if (lane == 0) wpair[t] = make_float2(w1, w2);

  const float4* a1 = alpha4 + (size_t)e1 * 256;
  const float4* a2 = alpha4 + (size_t)e2 * 256;
  ushort4* X1 = (ushort4*)(Xs + (size_t)(2 * t) * DD);
  ushort4* X2 = (ushort4*)(Xs + (size_t)(2 * t + 1) * DD);
  #pragma unroll
  for (int r = 0; r < 4; ++r){
    int c = lane + 64 * r;
    float4 xf = xv[r];
    float4 av = a1[c];
    X1[c] = make_ushort4(f2bf(xf.x * av.x), f2bf(xf.y * av.y),
                         f2bf(xf.z * av.z), f2bf(xf.w * av.w));
    av = a2[c];
    X2[c] = make_ushort4(f2bf(xf.x * av.x), f2bf(xf.y * av.y),
                         f2bf(xf.z * av.z), f2bf(xf.w * av.w));
  }
}

// ---------------- GEMM: C[8192,4096] = Xs @ Wb^T, fused relu+bias+combine ----------------
// m201 GEOMETRY (256x256 tile, 8 waves 2Mx4N, wave tile 128x64, BK=64, 128KB
// dbuf LDS, 1 block/CU) under the r4-VERIFIED schedule: whole-tile stage ->
// vmcnt(8) -> barrier -> 24 ds_read_b128 -> 64 MFMA (16x16x32) -> lgkm+barrier.
// LDS:MFMA byte ratio 384B/MFMA vs r4's 512B (LDS-BW was the binding limit).
// Same verified XOR chunk swizzle (c ^= row&7, pre-swizzled source).
#define BM 256
#define BN 256
#define BKT 64
#define NKT (DD / BKT)     // 16
#define ASZ (BM * BKT)     // 16384 elems = 32KB per slot per operand

__global__ __launch_bounds__(512, 1) void gemm_kernel(const unsigned short* __restrict__ Xs,
                                                      const unsigned short* __restrict__ Wb,
                                                      const float* __restrict__ bias,
                                                      const float2* __restrict__ wpair,
                                                      float* __restrict__ out){
  __shared__ __align__(16) unsigned short As[2 * ASZ]; // 64 KB
  __shared__ __align__(16) unsigned short Bs[2 * ASZ]; // 64 KB

  int tid = threadIdx.x, lane = tid & 63, wv = tid >> 6;
  int wr = wv >> 2, wc = wv & 3;            // wave tile 128x64
  int l15 = lane & 15;

  // XCD swizzle: 512 blocks = 8 chunks x 64; chunk -> 4 mtiles x 16 ntiles
  int bid = blockIdx.x;
  int ch = bid & 7, local = bid >> 3;
  int mtile = ch * 4 + (local & 3);         // 0..31
  int ntile = local >> 2;                   // 0..15
  int bm0 = mtile * BM, bn0 = ntile * BN;

  // --- staging: 512 thr x 16B = 64 rows per load; 4 loads cover 256 rows ---
  int sr = tid >> 3;                        // 0..63
  int sc = tid & 7;
  int scg = sc ^ (sr & 7);                  // involution; row&7 == sr&7 for all j
  const unsigned short* gA = Xs + (size_t)(bm0 + sr) * DD + scg * 8;
  const unsigned short* gB = Wb + (size_t)(bn0 + sr) * DD + scg * 8;
  unsigned short* lA = As + tid * 8;
  unsigned short* lB = Bs + tid * 8;

  auto stage = [&](int kt, int slot){
    int koff = kt * BKT;
    #pragma unroll
    for (int j = 0; j < 4; ++j)
      gload16(gA + (size_t)(64 * j) * DD + koff, lA + slot * ASZ + j * 4096);
    #pragma unroll
    for (int j = 0; j < 4; ++j)
      gload16(gB + (size_t)(64 * j) * DD + koff, lB + slot * ASZ + j * 4096);
  };

  // --- read addressing (r4-verified pattern: 0 bank conflicts) ---
  int r7 = l15 & 7;
  int posr0 = (lane >> 4) ^ r7;             // ks=0 chunk
  int posr1 = (4 + (lane >> 4)) ^ r7;       // ks=1 chunk

  f32x4 acc[8][4] = {};

  stage(0, 0);
  #pragma unroll 1
  for (int t = 0; t < NKT; ++t){
    int slot = t & 1;
    if (t < NKT - 1){
      stage(t + 1, slot ^ 1);
      asm volatile("s_waitcnt vmcnt(8)" ::: "memory");  // tile t resident
    } else {
      asm volatile("s_waitcnt vmcnt(0)" ::: "memory");
    }
    __builtin_amdgcn_s_barrier();

    const unsigned short* Ab = As + slot * ASZ;
    const unsigned short* Bb = Bs + slot * ASZ;

    #pragma unroll
    for (int ks = 0; ks < 2; ++ks){
      int pos = ks ? posr1 : posr0;
      bf16x8 af[8], bfr[4];
      #pragma unroll
      for (int mi = 0; mi < 8; ++mi)
        af[mi] = *(const bf16x8*)(Ab + (wr * 128 + mi * 16 + l15) * BKT + pos * 8);
      #pragma unroll
      for (int ni = 0; ni < 4; ++ni)
        bfr[ni] = *(const bf16x8*)(Bb + (wc * 64 + ni * 16 + l15) * BKT + pos * 8);

      __builtin_amdgcn_s_setprio(1);
      #pragma unroll
      for (int ni = 0; ni < 4; ++ni)
        #pragma unroll
        for (int mi = 0; mi < 8; ++mi)
          acc[mi][ni] = __builtin_amdgcn_mfma_f32_16x16x32_bf16(af[mi], bfr[ni],
                                                               acc[mi][ni], 0, 0, 0);
      __builtin_amdgcn_s_setprio(0);
    }

    asm volatile("s_waitcnt lgkmcnt(0)" ::: "memory");   // slot reads drained (WAR)
    __builtin_amdgcn_s_barrier();
  }

  // epilogue (validated in r5/r6): rows 2t / 2t+1 lane-local -> fused combine
  #pragma unroll
  for (int mi = 0; mi < 8; ++mi){
    int rbase = bm0 + wr * 128 + mi * 16 + ((lane >> 4) << 2);
    #pragma unroll
    for (int jp = 0; jp < 2; ++jp){
      int gm = rbase + jp * 2;  // even
      int tt = gm >> 1;
      float2 w = wpair[tt];
      #pragma unroll
      for (int ni = 0; ni < 4; ++ni){
        int gh = bn0 + wc * 64 + ni * 16 + l15;
        float bz = bias[gh];
        float v0 = acc[mi][ni][jp * 2]     + bz;
        float v1 = acc[mi][ni][jp * 2 + 1] + bz;
        out[(size_t)tt * HH + gh] = w.x * fmaxf(v0, 0.f) + w.y * fmaxf(v1, 0.f);
      }
    }
  }
}

extern "C" void kernel_launch(void* const* d_in, const int* in_sizes, int n_in,
                              void* d_out, int out_size, void* d_ws, size_t ws_size,
                              hipStream_t stream) {
  const float* x     = (const float*)d_in[0];
  const float* W     = (const float*)d_in[1];
  const float* bias  = (const float*)d_in[2];
  const float* alpha = (const float*)d_in[3];
  const float* beta  = (const float*)d_in[4];
  float* out = (float*)d_out;

  char* ws = (char*)d_ws;
  unsigned short* Wb = (unsigned short*)ws;                       // 8 MB
  unsigned short* Xs = (unsigned short*)(ws + (8u << 20));        // 16 MB
  float2* wpair      = (float2*)(ws + (24u << 20));               // 32 KB
  double* bmean      = (double*)(ws + (24u << 20) + (64u << 10)); // 8 B
  float* pmean       = (float*)(ws + (24u << 20) + (128u << 10)); // 512 KB
  float* pm2         = pmean + 128 * DD;                          // 512 KB
  float* muw         = (float*)(ws + (26u << 20));                // 32 KB
  float* vw          = muw + EE * DD;                             // 32 KB

  cvtstats_kernel<<<128, 256, 0, stream>>>((const float4*)W, (ushort4*)Wb, pmean, pm2);
  finalize_kernel<<<4, 256, 0, stream>>>(pmean, pm2, bias, alpha, beta, bmean, muw, vw);
  router_kernel<<<MTOK / 4, 256, 0, stream>>>((const float4*)x, (const float4*)alpha,
                                              (const float4*)muw, (const float4*)vw,
                                              bmean, Xs, wpair);
  gemm_kernel<<<(MROWS / BM) * (HH / BN), 512, 0, stream>>>(Xs, Wb, bias, wpair, out);
}